// Round 17
// baseline (647.170 us; speedup 1.0000x reference)
//
#include <hip/hip_runtime.h>
#include <math.h>

// ImplicitFlowDecoder round 17: r16 (643us, proven) + two serial-path trims:
//  * hw1 scal rows 256-259 (4KB fp32) staged into LDS (removes 8 global float4
//    loads/wave from head1's post-gemm serial epilogues).
//  * sIdx packed to uchar4-in-uint (3KB -> 0.75KB) so LDS stays 2 blocks/CU
//    (total 80384B; 2x = 160.8KB < 163.8KB).
// Ledger/barriers/staging/gemm cores byte-identical to r16.

typedef _Float16 half8 __attribute__((ext_vector_type(8)));
typedef _Float16 half4v __attribute__((ext_vector_type(4)));
typedef _Float16 half2v __attribute__((ext_vector_type(2)));
typedef float floatx4 __attribute__((ext_vector_type(4)));

#define NPOINTS_TOTAL (2 * 384 * 512)
#define PPB 64
#define NBLOCKS (NPOINTS_TOTAL / PPB)    // 6144
#define PTS_PER_IMG 196608
#define BLOCKS_PER_IMG 3072

#define WS_CTX   0
#define WS_F1W1  8192
#define WS_F1W2  40960
#define WS_S8    73728
#define WS_F2W1  90112
#define WS_F2W2  122880
#define WS_HW1   155648
#define WS_HW2   221184
#define WS_HW3   253952

// sBias layout (floats)
#define SB_CTXB  0
#define SB_GATE1 128
#define SB_F1B1  256
#define SB_F1B2  512
#define SB_S8B   640
#define SB_GATE2 768
#define SB_F2B1  896
#define SB_F2B2  1152
#define SB_HB1   1280
#define SB_HB2   1536
#define SB_HB3   1664
#define SB_SCALW 1728          // hw1 rows 256..259 (4 x 256 floats)
#define SB_TOT   2752

__device__ __forceinline__ float sigmoidf_(float x) { return 1.0f / (1.0f + expf(-x)); }
__device__ __forceinline__ float geluf_(float x) {
    const float ax = fabsf(x) * 0.70710678118654752f;
    const float t = 1.0f / fmaf(0.3275911f, ax, 1.0f);
    float poly = fmaf(t, 1.061405429f, -1.453152027f);
    poly = fmaf(t, poly, 1.421413741f);
    poly = fmaf(t, poly, -0.284496736f);
    poly = fmaf(t, poly, 0.254829592f);
    poly *= t;
    float er = 1.0f - poly * expf(-ax * ax);
    er = copysignf(er, x);
    return 0.5f * x * (1.0f + er);
}
__device__ __forceinline__ int swz(int pt) { return (pt & 15) << 3; }

// ---------------- prepack: W[K][N] fp32 -> f16 fragments -------------------
__global__ void prepack_kernel(const float* __restrict__ ctx_w, const float* __restrict__ f1w1,
                               const float* __restrict__ f1w2, const float* __restrict__ s8w,
                               const float* __restrict__ f2w1, const float* __restrict__ f2w2,
                               const float* __restrict__ hw1, const float* __restrict__ hw2,
                               const float* __restrict__ hw3, _Float16* __restrict__ ws) {
    const int bid = blockIdx.x;
    const int lane = threadIdx.x;
    const float* src; int N, CT, start; size_t ofsH;
    if (bid < 16)       { src = ctx_w; N = 128; CT = 8;  start = 0;   ofsH = WS_CTX; }
    else if (bid < 80)  { src = f1w1;  N = 256; CT = 16; start = 16;  ofsH = WS_F1W1; }
    else if (bid < 144) { src = f1w2;  N = 128; CT = 8;  start = 80;  ofsH = WS_F1W2; }
    else if (bid < 176) { src = s8w;   N = 128; CT = 8;  start = 144; ofsH = WS_S8; }
    else if (bid < 240) { src = f2w1;  N = 256; CT = 16; start = 176; ofsH = WS_F2W1; }
    else if (bid < 304) { src = f2w2;  N = 128; CT = 8;  start = 240; ofsH = WS_F2W2; }
    else if (bid < 432) { src = hw1;   N = 256; CT = 16; start = 304; ofsH = WS_HW1; }
    else if (bid < 496) { src = hw2;   N = 128; CT = 8;  start = 432; ofsH = WS_HW2; }
    else                { src = hw3;   N = 64;  CT = 4;  start = 496; ofsH = WS_HW3; }
    const int ti = bid - start;
    const int ks = ti / CT, ct = ti % CT;
    const int m = lane & 15, g = lane >> 4;
    const int kb = ks * 32 + g * 8;
    const int n = ct * 16 + m;
    half8 v;
#pragma unroll
    for (int j = 0; j < 8; ++j) v[j] = (_Float16)src[(size_t)(kb + j) * N + n];
    *reinterpret_cast<half8*>(ws + ofsH + (size_t)ti * 512 + lane * 8) = v;
}

// ---------------- async chunk staging (identical to r13/r16) ---------------
template <int NT, int CTc>
__device__ __forceinline__ void stageChunk(const _Float16* __restrict__ src, int cts,
                                           int ks0, int ct0, _Float16* wdst,
                                           int wid, int lane) {
#pragma unroll
    for (int jj = 0; jj < NT / 4; ++jj) {
        const int j = wid * (NT / 4) + jj;
        const int ks = j / CTc, ct = j - ks * CTc;
        const _Float16* s = src + (((size_t)(ks0 + ks) * cts + (ct0 + ct)) << 9) + lane * 8;
        _Float16* d = wdst + ((size_t)j << 9);
        __builtin_amdgcn_global_load_lds(
            (const __attribute__((address_space(1))) unsigned int*)s,
            (__attribute__((address_space(3))) unsigned int*)d, 16, 0, 0);
    }
}

// ---------------- GEMM chunk cores (quadrant: 4 ct tiles x 2 pt-groups) ----
template <int KSc>
__device__ __forceinline__ void gemmChunkQ(floatx4 (&acc)[4][2], const _Float16* wlds,
                                           const _Float16* sact, int kbase,
                                           int ctb, int ptb, int lane) {
    const int m = lane & 15, g = lane >> 4;
    const int pt0 = ptb + m, pt1 = pt0 + 16;
    const int s0 = swz(pt0), s1 = swz(pt1);
    const _Float16* wb = wlds + lane * 8;
    __builtin_amdgcn_s_setprio(1);
#pragma unroll
    for (int ks = 0; ks < KSc; ++ks) {
        const int k0 = (kbase + ks) * 32 + g * 8;
        half8 a0 = *reinterpret_cast<const half8*>(sact + pt0 * 128 + (k0 ^ s0));
        half8 a1 = *reinterpret_cast<const half8*>(sact + pt1 * 128 + (k0 ^ s1));
#pragma unroll
        for (int c = 0; c < 4; ++c) {
            half8 w = *reinterpret_cast<const half8*>(wb + ((size_t)(ks * 8 + ctb + c) << 9));
            acc[c][0] = __builtin_amdgcn_mfma_f32_16x16x32_f16(w, a0, acc[c][0], 0, 0, 0);
            acc[c][1] = __builtin_amdgcn_mfma_f32_16x16x32_f16(w, a1, acc[c][1], 0, 0, 0);
        }
    }
    __builtin_amdgcn_s_setprio(0);
}

template <int KSc>
__device__ __forceinline__ void gemmChunkRegBQ(floatx4 (&acc)[4][2], const _Float16* wlds,
                                               const half8 (&fr)[4][2], int frbase,
                                               int ctb, int lane) {
    const _Float16* wb = wlds + lane * 8;
    __builtin_amdgcn_s_setprio(1);
#pragma unroll
    for (int ks = 0; ks < KSc; ++ks) {
#pragma unroll
        for (int c = 0; c < 4; ++c) {
            half8 w = *reinterpret_cast<const half8*>(wb + ((size_t)(ks * 8 + ctb + c) << 9));
            acc[c][0] = __builtin_amdgcn_mfma_f32_16x16x32_f16(w, fr[frbase + ks][0], acc[c][0], 0, 0, 0);
            acc[c][1] = __builtin_amdgcn_mfma_f32_16x16x32_f16(w, fr[frbase + ks][1], acc[c][1], 0, 0, 0);
        }
    }
    __builtin_amdgcn_s_setprio(0);
}

// head3 (4 ct tiles total, CTc=4 layout): quadrant = 2 ct tiles x 2 pt-groups
__device__ __forceinline__ void gemmChunkH3(floatx4 (&acc)[2][2], const _Float16* wlds,
                                            const _Float16* sact, int ctb2, int ptb, int lane) {
    const int m = lane & 15, g = lane >> 4;
    const int pt0 = ptb + m, pt1 = pt0 + 16;
    const int s0 = swz(pt0), s1 = swz(pt1);
    const _Float16* wb = wlds + lane * 8;
    __builtin_amdgcn_s_setprio(1);
#pragma unroll
    for (int ks = 0; ks < 4; ++ks) {
        const int k0 = ks * 32 + g * 8;
        half8 a0 = *reinterpret_cast<const half8*>(sact + pt0 * 128 + (k0 ^ s0));
        half8 a1 = *reinterpret_cast<const half8*>(sact + pt1 * 128 + (k0 ^ s1));
#pragma unroll
        for (int c = 0; c < 2; ++c) {
            half8 w = *reinterpret_cast<const half8*>(wb + ((size_t)(ks * 4 + ctb2 + c) << 9));
            acc[c][0] = __builtin_amdgcn_mfma_f32_16x16x32_f16(w, a0, acc[c][0], 0, 0, 0);
            acc[c][1] = __builtin_amdgcn_mfma_f32_16x16x32_f16(w, a1, acc[c][1], 0, 0, 0);
        }
    }
    __builtin_amdgcn_s_setprio(0);
}

__device__ __forceinline__ void loadFragsQ(half8 (&fr)[4][2], const _Float16* sact,
                                           int ptb, int lane) {
    const int m = lane & 15, g = lane >> 4;
    const int pt0 = ptb + m, pt1 = pt0 + 16;
    const int s0 = swz(pt0), s1 = swz(pt1);
#pragma unroll
    for (int ks = 0; ks < 4; ++ks) {
        const int k0 = ks * 32 + g * 8;
        fr[ks][0] = *reinterpret_cast<const half8*>(sact + pt0 * 128 + (k0 ^ s0));
        fr[ks][1] = *reinterpret_cast<const half8*>(sact + pt1 * 128 + (k0 ^ s1));
    }
}

__device__ __forceinline__ void storeH4(_Float16* dst, int pt, int ch0,
                                        float o0, float o1, float o2, float o3) {
    half4v hv;
    hv[0] = (_Float16)o0; hv[1] = (_Float16)o1; hv[2] = (_Float16)o2; hv[3] = (_Float16)o3;
    *reinterpret_cast<half4v*>(dst + pt * 128 + (ch0 ^ swz(pt))) = hv;
}
__device__ __forceinline__ half4v loadH4(const _Float16* src, int pt, int ch0) {
    return *reinterpret_cast<const half4v*>(src + pt * 128 + (ch0 ^ swz(pt)));
}

// ---------------- main kernel ----------------------------------------------
__global__ void __launch_bounds__(256, 2)
ifd_mfma(const float* __restrict__ feat_s8, const float* __restrict__ feat1_s8,
         const float* __restrict__ feat_s16, const float* __restrict__ ctx_s8,
         const float* __restrict__ coarse_flow,
         const float* __restrict__ ctx_b, const float* __restrict__ gate1,
         const float* __restrict__ ffn1_b1, const float* __restrict__ ffn1_b2,
         const float* __restrict__ s8_b, const float* __restrict__ gate2,
         const float* __restrict__ ffn2_b1, const float* __restrict__ ffn2_b2,
         const float* __restrict__ hw1, const float* __restrict__ hb1,
         const float* __restrict__ hb2, const float* __restrict__ hb3,
         const float* __restrict__ hw4, const float* __restrict__ hb4,
         const _Float16* __restrict__ wsp, float* __restrict__ out) {
    __shared__ __align__(16) _Float16 bufA[64 * 128];      // 16KB
    __shared__ __align__(16) _Float16 bufB[64 * 128];      // 16KB
    __shared__ __align__(16) _Float16 wBuf[2][8192];       // 2x16KB weight chunks
    __shared__ __align__(16) float sBias[SB_TOT];          // 10.75KB (biases+gates+scalW)
    __shared__ float sScal[4 * 64];
    __shared__ float sCps[2 * 64];
    __shared__ unsigned sIdxP[3 * 64];                     // packed x0|x1<<8|y0<<16|y1<<24
    __shared__ float sWgt[3 * 2 * 64];

    const int t = threadIdx.x;
    const int lane = t & 63, wid = t >> 6;           // 4 waves
    const int m = lane & 15, g = lane >> 4;
    const int ctb = (wid & 1) * 4;                    // ct-tile quadrant base (0 or 4)
    const int ptb = (wid >> 1) * 32;                  // point quadrant base (0 or 32)
    const int b = blockIdx.x / BLOCKS_PER_IMG;
    const int qbase = blockIdx.x * PPB;
    const float CHI = 1.0f - 1e-6f;

    // ---------- biases/gates + hw1 scal rows -> LDS
    if (t < 128) {
        sBias[SB_CTXB + t] = ctx_b[t];
        sBias[SB_GATE1 + t] = gate1[t];
        sBias[SB_F1B2 + t] = ffn1_b2[t];
        sBias[SB_S8B + t] = s8_b[t];
        sBias[SB_GATE2 + t] = gate2[t];
        sBias[SB_F2B2 + t] = ffn2_b2[t];
        sBias[SB_HB2 + t] = hb2[t];
    }
    sBias[SB_F1B1 + t] = ffn1_b1[t];
    sBias[SB_F2B1 + t] = ffn2_b1[t];
    sBias[SB_HB1 + t] = hb1[t];
    if (t < 64) sBias[SB_HB3 + t] = hb3[t];
#pragma unroll
    for (int i = t; i < 1024; i += 256)
        sBias[SB_SCALW + i] = hw1[(size_t)(256 + (i >> 8)) * 256 + (i & 255)];

    // ---------- coords + coarse flow + warp (threads 0..63, 1 pt each)
    if (t < 64) {
        const int p = t;
        const int rem = qbase + p - b * PTS_PER_IMG;
        const int gy = rem >> 9, gx = rem & 511;
        float cnx = fminf(fmaxf(2.0f * ((float)gx + 0.5f) / 512.0f - 1.0f, -CHI), CHI);
        float cny = fminf(fmaxf(2.0f * ((float)gy + 0.5f) / 384.0f - 1.0f, -CHI), CHI);

        auto mkc = [](float cn, float Sf, int Smax, int& i0, int& i1, float& w) {
            float x = fminf(fmaxf(((cn + 1.0f) * Sf - 1.0f) * 0.5f, 0.0f), Sf - 1.0f);
            float xf = floorf(x);
            w = x - xf;
            i0 = (int)xf;
            i1 = (i0 + 1 > Smax) ? Smax : i0 + 1;
        };
        auto storeSet = [&](int s, int x0, int x1, int y0, int y1, float wx, float wy) {
            sIdxP[s * 64 + p] = (unsigned)x0 | ((unsigned)x1 << 8) |
                                ((unsigned)y0 << 16) | ((unsigned)y1 << 24);
            sWgt[s * 128 + p] = wx; sWgt[s * 128 + 64 + p] = wy;
        };

        int x0, x1, y0, y1; float wx, wy;
        mkc(cnx, 64.0f, 63, x0, x1, wx);
        mkc(cny, 48.0f, 47, y0, y1, wy);
        storeSet(0, x0, x1, y0, y1, wx, wy);

        int X0, X1, Y0, Y1; float WX, WY;
        mkc(cnx, 32.0f, 31, X0, X1, WX);
        mkc(cny, 24.0f, 23, Y0, Y1, WY);
        storeSet(1, X0, X1, Y0, Y1, WX, WY);

        const float w00 = (1.0f - wx) * (1.0f - wy), w01 = wx * (1.0f - wy);
        const float w10 = (1.0f - wx) * wy, w11 = wx * wy;
        const int i00 = y0 * 64 + x0, i01 = y0 * 64 + x1, i10 = y1 * 64 + x0, i11 = y1 * 64 + x1;
        const float* cf = coarse_flow + (size_t)b * 6144;
        float c0 = (cf[i00] * w00 + cf[i01] * w01 + cf[i10] * w10 + cf[i11] * w11) * 8.0f;
        const float* cf1 = cf + 3072;
        float c1 = (cf1[i00] * w00 + cf1[i01] * w01 + cf1[i10] * w10 + cf1[i11] * w11) * 8.0f;
        sCps[p] = c0; sCps[64 + p] = c1;
        sScal[p] = cnx; sScal[64 + p] = cny;
        sScal[128 + p] = c0 / 512.0f; sScal[192 + p] = c1 / 384.0f;

        float wxn = fminf(fmaxf(cnx + 2.0f * c0 / 512.0f, -CHI), CHI);
        float wyn = fminf(fmaxf(cny + 2.0f * c1 / 384.0f, -CHI), CHI);
        int u0, u1, v0, v1; float uw, vw;
        mkc(wxn, 64.0f, 63, u0, u1, uw);
        mkc(wyn, 48.0f, 47, v0, v1, vw);
        storeSet(2, u0, u1, v0, v1, uw, vw);
    }

    // prologue: issue first chunk stage into wBuf[0]
    stageChunk<16, 8>(wsp + WS_CTX, 8, 0, 0, wBuf[0], wid, lane);
    __syncthreads();

    // thread t samples point (t&63), channel-quarter (t>>6)
    auto sampleMap = [&](const float* __restrict__ mapB, int C, int HW, int Wd, int set,
                         _Float16* dst) {
        const int pt = t & 63, hs = t >> 6;
        const unsigned pk = sIdxP[set * 64 + pt];
        const int x0 = (int)(pk & 255u), x1 = (int)((pk >> 8) & 255u);
        const int y0 = (int)((pk >> 16) & 255u), y1 = (int)(pk >> 24);
        const float wx = sWgt[set * 128 + pt], wy = sWgt[set * 128 + 64 + pt];
        const float w00 = (1.0f - wx) * (1.0f - wy), w01 = wx * (1.0f - wy);
        const float w10 = (1.0f - wx) * wy, w11 = wx * wy;
        const int i00 = y0 * Wd + x0, i01 = y0 * Wd + x1, i10 = y1 * Wd + x0, i11 = y1 * Wd + x1;
        const int np = C >> 3;
#pragma unroll 4
        for (int i = 0; i < np; ++i) {
            const int c0 = hs * (C >> 2) + 2 * i;
            const float* p0 = mapB + (size_t)c0 * HW;
            const float* p1 = p0 + HW;
            float v0 = p0[i00] * w00 + p0[i01] * w01 + p0[i10] * w10 + p0[i11] * w11;
            float v1 = p1[i00] * w00 + p1[i01] * w01 + p1[i10] * w10 + p1[i11] * w11;
            half2v hv; hv[0] = (_Float16)v0; hv[1] = (_Float16)v1;
            *reinterpret_cast<half2v*>(dst + pt * 128 + (c0 ^ swz(pt))) = hv;
        }
    };

    // ---------- sample f8 -> bufA, fctx -> bufB[:,0:64]
    sampleMap(feat_s8 + (size_t)b * 128 * 3072, 128, 3072, 64, 0, bufA);
    sampleMap(ctx_s8 + (size_t)b * 64 * 3072, 64, 3072, 64, 0, bufB);
    __syncthreads();

    int cur = 0;
    floatx4 acc[4][2];

#define RESETQ() do { _Pragma("unroll") for (int _c = 0; _c < 4; ++_c) \
    { acc[_c][0] = (floatx4)0.0f; acc[_c][1] = (floatx4)0.0f; } } while (0)
#define STEP_END() do { __syncthreads(); cur ^= 1; } while (0)

#define EPI_LOOP(BODY) do { \
    _Pragma("unroll") for (int c = 0; c < 4; ++c) { \
        const int ch0 = (ctb + c) * 16 + g * 4; \
        _Pragma("unroll") for (int pg = 0; pg < 2; ++pg) { \
            const int pt2 = ptb + pg * 16 + m; \
            floatx4 v = acc[c][pg]; \
            BODY \
        } } } while (0)

    // ---- ctx: C0 (2ks, bufB) + epi gate1 -> bufA (residual own quadrant, safe)
    stageChunk<16, 8>(wsp + WS_F1W1, 16, 0, 0, wBuf[cur ^ 1], wid, lane);    // C1
    RESETQ();
    gemmChunkQ<2>(acc, wBuf[cur], bufB, 0, ctb, ptb, lane);
    EPI_LOOP({
        const float4 bb = *reinterpret_cast<const float4*>(sBias + SB_CTXB + ch0);
        const float4 gg = *reinterpret_cast<const float4*>(sBias + SB_GATE1 + ch0);
        half4v rv = loadH4(bufA, pt2, ch0);
        storeH4(bufA, pt2, ch0,
                (float)rv[0] + sigmoidf_(gg.x) * (v[0] + bb.x),
                (float)rv[1] + sigmoidf_(gg.y) * (v[1] + bb.y),
                (float)rv[2] + sigmoidf_(gg.z) * (v[2] + bb.z),
                (float)rv[3] + sigmoidf_(gg.w) * (v[3] + bb.w));
    });
    STEP_END();

    // ---- ffn1_w1 half0: C1 + C2, epi gelu -> bufB (bufB dead, safe)
    stageChunk<16, 8>(wsp + WS_F1W1, 16, 2, 0, wBuf[cur ^ 1], wid, lane);    // C2
    RESETQ();
    gemmChunkQ<2>(acc, wBuf[cur], bufA, 0, ctb, ptb, lane);
    STEP_END();
    stageChunk<16, 8>(wsp + WS_F1W1, 16, 0, 8, wBuf[cur ^ 1], wid, lane);    // C3
    gemmChunkQ<2>(acc, wBuf[cur], bufA, 2, ctb, ptb, lane);
    EPI_LOOP({
        const float4 bb = *reinterpret_cast<const float4*>(sBias + SB_F1B1 + ch0);
        storeH4(bufB, pt2, ch0, geluf_(v[0] + bb.x), geluf_(v[1] + bb.y),
                geluf_(v[2] + bb.z), geluf_(v[3] + bb.w));
    });
    STEP_END();

    // ---- ffn1_w1 half1: C3 + C4, epi gelu -> bufA IN-PLACE (barrier before write)
    stageChunk<16, 8>(wsp + WS_F1W1, 16, 2, 8, wBuf[cur ^ 1], wid, lane);    // C4
    RESETQ();
    gemmChunkQ<2>(acc, wBuf[cur], bufA, 0, ctb, ptb, lane);
    STEP_END();
    stageChunk<16, 8>(wsp + WS_F1W2, 8, 0, 0, wBuf[cur ^ 1], wid, lane);     // C5
    gemmChunkQ<2>(acc, wBuf[cur], bufA, 2, ctb, ptb, lane);
    __syncthreads();   // RACE FIX: partner still reading bufA ch64-127
    EPI_LOOP({
        const float4 bb = *reinterpret_cast<const float4*>(sBias + SB_F1B1 + 128 + ch0);
        storeH4(bufA, pt2, ch0, geluf_(v[0] + bb.x), geluf_(v[1] + bb.y),
                geluf_(v[2] + bb.z), geluf_(v[3] + bb.w));
    });
    STEP_END();

    // ---- ffn1_w2: C5-C8 (bufB k0-3, bufA k0-3), epi -> bufA IN-PLACE
    stageChunk<16, 8>(wsp + WS_F1W2, 8, 2, 0, wBuf[cur ^ 1], wid, lane);     // C6
    RESETQ();
    gemmChunkQ<2>(acc, wBuf[cur], bufB, 0, ctb, ptb, lane);
    STEP_END();
    stageChunk<16, 8>(wsp + WS_F1W2, 8, 4, 0, wBuf[cur ^ 1], wid, lane);     // C7
    gemmChunkQ<2>(acc, wBuf[cur], bufB, 2, ctb, ptb, lane);
    STEP_END();
    stageChunk<16, 8>(wsp + WS_F1W2, 8, 6, 0, wBuf[cur ^ 1], wid, lane);     // C8
    gemmChunkQ<2>(acc, wBuf[cur], bufA, 0, ctb, ptb, lane);
    STEP_END();
    stageChunk<16, 8>(wsp + WS_S8, 8, 0, 0, wBuf[cur ^ 1], wid, lane);       // C9
    gemmChunkQ<2>(acc, wBuf[cur], bufA, 2, ctb, ptb, lane);
    __syncthreads();   // RACE FIX
    EPI_LOOP({
        const float4 bb = *reinterpret_cast<const float4*>(sBias + SB_F1B2 + ch0);
        storeH4(bufA, pt2, ch0, v[0] + bb.x, v[1] + bb.y, v[2] + bb.z, v[3] + bb.w);
    });
    STEP_END();

    // ---- sample f16 -> bufB
    sampleMap(feat_s16 + (size_t)b * 128 * 768, 128, 768, 32, 1, bufB);
    __syncthreads();

    // ---- s8: C9 + C10 (bufA), epi gate2 + f16 -> bufB (residual own quadrant, safe)
    stageChunk<16, 8>(wsp + WS_S8, 8, 2, 0, wBuf[cur ^ 1], wid, lane);       // C10
    RESETQ();
    gemmChunkQ<2>(acc, wBuf[cur], bufA, 0, ctb, ptb, lane);
    STEP_END();
    stageChunk<16, 8>(wsp + WS_F2W1, 16, 0, 0, wBuf[cur ^ 1], wid, lane);    // C11
    gemmChunkQ<2>(acc, wBuf[cur], bufA, 2, ctb, ptb, lane);
    EPI_LOOP({
        const float4 bb = *reinterpret_cast<const float4*>(sBias + SB_S8B + ch0);
        const float4 gg = *reinterpret_cast<const float4*>(sBias + SB_GATE2 + ch0);
        half4v rv = loadH4(bufB, pt2, ch0);
        storeH4(bufB, pt2, ch0,
                (float)rv[0] + sigmoidf_(gg.x) * (v[0] + bb.x),
                (float)rv[1] + sigmoidf_(gg.y) * (v[1] + bb.y),
                (float)rv[2] + sigmoidf_(gg.z) * (v[2] + bb.z),
                (float)rv[3] + sigmoidf_(gg.w) * (v[3] + bb.w));
    });
    STEP_END();

    // ---- ffn2_w1 half0: C11 + C12 (bufB), epi gelu -> bufA (bufA dead, safe)
    stageChunk<16, 8>(wsp + WS_F2W1, 16, 2, 0, wBuf[cur ^ 1], wid, lane);    // C12
    RESETQ();
    gemmChunkQ<2>(acc, wBuf[cur], bufB, 0, ctb, ptb, lane);
    STEP_END();
    stageChunk<16, 8>(wsp + WS_F2W1, 16, 0, 8, wBuf[cur ^ 1], wid, lane);    // C13
    gemmChunkQ<2>(acc, wBuf[cur], bufB, 2, ctb, ptb, lane);
    EPI_LOOP({
        const float4 bb = *reinterpret_cast<const float4*>(sBias + SB_F2B1 + ch0);
        storeH4(bufA, pt2, ch0, geluf_(v[0] + bb.x), geluf_(v[1] + bb.y),
                geluf_(v[2] + bb.z), geluf_(v[3] + bb.w));
    });
    STEP_END();

    // ---- ffn2_w1 half1: C13 + C14 (bufB), epi gelu -> bufB IN-PLACE
    stageChunk<16, 8>(wsp + WS_F2W1, 16, 2, 8, wBuf[cur ^ 1], wid, lane);    // C14
    RESETQ();
    gemmChunkQ<2>(acc, wBuf[cur], bufB, 0, ctb, ptb, lane);
    STEP_END();
    stageChunk<16, 8>(wsp + WS_F2W2, 8, 0, 0, wBuf[cur ^ 1], wid, lane);     // C15
    gemmChunkQ<2>(acc, wBuf[cur], bufB, 2, ctb, ptb, lane);
    __syncthreads();   // RACE FIX
    EPI_LOOP({
        const float4 bb = *reinterpret_cast<const float4*>(sBias + SB_F2B1 + 128 + ch0);
        storeH4(bufB, pt2, ch0, geluf_(v[0] + bb.x), geluf_(v[1] + bb.y),
                geluf_(v[2] + bb.z), geluf_(v[3] + bb.w));
    });
    STEP_END();

    // ---- ffn2_w2: C15-C18 (bufA k0-3, bufB k0-3), epi fused -> bufB IN-PLACE
    stageChunk<16, 8>(wsp + WS_F2W2, 8, 2, 0, wBuf[cur ^ 1], wid, lane);     // C16
    RESETQ();
    gemmChunkQ<2>(acc, wBuf[cur], bufA, 0, ctb, ptb, lane);
    STEP_END();
    stageChunk<16, 8>(wsp + WS_F2W2, 8, 4, 0, wBuf[cur ^ 1], wid, lane);     // C17
    gemmChunkQ<2>(acc, wBuf[cur], bufA, 2, ctb, ptb, lane);
    STEP_END();
    stageChunk<16, 8>(wsp + WS_F2W2, 8, 6, 0, wBuf[cur ^ 1], wid, lane);     // C18
    gemmChunkQ<2>(acc, wBuf[cur], bufB, 0, ctb, ptb, lane);
    STEP_END();
    stageChunk<16, 8>(wsp + WS_HW1, 16, 0, 0, wBuf[cur ^ 1], wid, lane);     // C19
    gemmChunkQ<2>(acc, wBuf[cur], bufB, 2, ctb, ptb, lane);
    __syncthreads();   // RACE FIX
    EPI_LOOP({
        const float4 bb = *reinterpret_cast<const float4*>(sBias + SB_F2B2 + ch0);
        storeH4(bufB, pt2, ch0, v[0] + bb.x, v[1] + bb.y, v[2] + bb.z, v[3] + bb.w);
    });
    STEP_END();

    // ---- sample f1w -> bufA
    sampleMap(feat1_s8 + (size_t)b * 128 * 3072, 128, 3072, 64, 2, bufA);
    __syncthreads();

    // ---- head1 hf0: C19,C20 (bufB) + C21,C22 (f1w regs), epi scal+relu -> bufA
    half8 fr[4][2];
    loadFragsQ(fr, bufA, ptb, lane);   // all waves load before any barrier-crossing write
    stageChunk<16, 8>(wsp + WS_HW1, 16, 2, 0, wBuf[cur ^ 1], wid, lane);     // C20
    RESETQ();
    gemmChunkQ<2>(acc, wBuf[cur], bufB, 0, ctb, ptb, lane);
    STEP_END();
    stageChunk<16, 8>(wsp + WS_HW1, 16, 4, 0, wBuf[cur ^ 1], wid, lane);     // C21
    gemmChunkQ<2>(acc, wBuf[cur], bufB, 2, ctb, ptb, lane);
    STEP_END();
    stageChunk<16, 8>(wsp + WS_HW1, 16, 6, 0, wBuf[cur ^ 1], wid, lane);     // C22
    gemmChunkRegBQ<2>(acc, wBuf[cur], fr, 0, ctb, lane);
    STEP_END();
    stageChunk<16, 8>(wsp + WS_HW1, 16, 0, 8, wBuf[cur ^ 1], wid, lane);     // C23
    gemmChunkRegBQ<2>(acc, wBuf[cur], fr, 2, ctb, lane);
#pragma unroll
    for (int c = 0; c < 4; ++c) {
        const int ch0 = (ctb + c) * 16 + g * 4;
#pragma unroll
        for (int jj = 0; jj < 4; ++jj) {
            const float4 wj = *reinterpret_cast<const float4*>(sBias + SB_SCALW + jj * 256 + ch0);
#pragma unroll
            for (int pg = 0; pg < 2; ++pg) {
                const float s = sScal[jj * 64 + ptb + pg * 16 + m];
                floatx4 v = acc[c][pg];
                v[0] = fmaf(wj.x, s, v[0]); v[1] = fmaf(wj.y, s, v[1]);
                v[2] = fmaf(wj.z, s, v[2]); v[3] = fmaf(wj.w, s, v[3]);
                acc[c][pg] = v;
            }
        }
    }
    EPI_LOOP({
        const float4 bb = *reinterpret_cast<const float4*>(sBias + SB_HB1 + ch0);
        storeH4(bufA, pt2, ch0, fmaxf(v[0] + bb.x, 0.0f), fmaxf(v[1] + bb.y, 0.0f),
                fmaxf(v[2] + bb.z, 0.0f), fmaxf(v[3] + bb.w, 0.0f));
    });
    STEP_END();

    // ---- head1 hf1: C23,C24 (bufB) + C25,C26 (f1w regs), epi scal+relu -> bufB
    stageChunk<16, 8>(wsp + WS_HW1, 16, 2, 8, wBuf[cur ^ 1], wid, lane);     // C24
    RESETQ();
    gemmChunkQ<2>(acc, wBuf[cur], bufB, 0, ctb, ptb, lane);
    STEP_END();
    stageChunk<16, 8>(wsp + WS_HW1, 16, 4, 8, wBuf[cur ^ 1], wid, lane);     // C25
    gemmChunkQ<2>(acc, wBuf[cur], bufB, 2, ctb, ptb, lane);
    STEP_END();
    stageChunk<16, 8>(wsp + WS_HW1, 16, 6, 8, wBuf[cur ^ 1], wid, lane);     // C26
    gemmChunkRegBQ<2>(acc, wBuf[cur], fr, 0, ctb, lane);
    STEP_END();
    stageChunk<16, 8>(wsp + WS_HW2, 8, 0, 0, wBuf[cur ^ 1], wid, lane);      // C27
    gemmChunkRegBQ<2>(acc, wBuf[cur], fr, 2, ctb, lane);
#pragma unroll
    for (int c = 0; c < 4; ++c) {
        const int ch0 = (ctb + c) * 16 + g * 4;
#pragma unroll
        for (int jj = 0; jj < 4; ++jj) {
            const float4 wj = *reinterpret_cast<const float4*>(sBias + SB_SCALW + jj * 256 + 128 + ch0);
#pragma unroll
            for (int pg = 0; pg < 2; ++pg) {
                const float s = sScal[jj * 64 + ptb + pg * 16 + m];
                floatx4 v = acc[c][pg];
                v[0] = fmaf(wj.x, s, v[0]); v[1] = fmaf(wj.y, s, v[1]);
                v[2] = fmaf(wj.z, s, v[2]); v[3] = fmaf(wj.w, s, v[3]);
                acc[c][pg] = v;
            }
        }
    }
    EPI_LOOP({
        const float4 bb = *reinterpret_cast<const float4*>(sBias + SB_HB1 + 128 + ch0);
        storeH4(bufB, pt2, ch0, fmaxf(v[0] + bb.x, 0.0f), fmaxf(v[1] + bb.y, 0.0f),
                fmaxf(v[2] + bb.z, 0.0f), fmaxf(v[3] + bb.w, 0.0f));
    });
    STEP_END();

    // ---- head2: C27-C30 (bufA k0-3, bufB k0-3), epi relu -> bufA
    stageChunk<16, 8>(wsp + WS_HW2, 8, 2, 0, wBuf[cur ^ 1], wid, lane);      // C28
    RESETQ();
    gemmChunkQ<2>(acc, wBuf[cur], bufA, 0, ctb, ptb, lane);
    STEP_END();
    stageChunk<16, 8>(wsp + WS_HW2, 8, 4, 0, wBuf[cur ^ 1], wid, lane);      // C29
    gemmChunkQ<2>(acc, wBuf[cur], bufA, 2, ctb, ptb, lane);
    STEP_END();
    stageChunk<16, 8>(wsp + WS_HW2, 8, 6, 0, wBuf[cur ^ 1], wid, lane);      // C30
    gemmChunkQ<2>(acc, wBuf[cur], bufB, 0, ctb, ptb, lane);
    STEP_END();
    stageChunk<16, 4>(wsp + WS_HW3, 4, 0, 0, wBuf[cur ^ 1], wid, lane);      // C31 (all 16 tiles)
    gemmChunkQ<2>(acc, wBuf[cur], bufB, 2, ctb, ptb, lane);
    EPI_LOOP({
        const float4 bb = *reinterpret_cast<const float4*>(sBias + SB_HB2 + ch0);
        storeH4(bufA, pt2, ch0, fmaxf(v[0] + bb.x, 0.0f), fmaxf(v[1] + bb.y, 0.0f),
                fmaxf(v[2] + bb.z, 0.0f), fmaxf(v[3] + bb.w, 0.0f));
    });
    STEP_END();

    // ---- head3: C31 (4ks x 4ct layout, bufA), quadrant 2ct x 2pg -> bufB[:,0:64]
    {
        const int ctb2 = (wid & 1) * 2;
        floatx4 a3[2][2];
#pragma unroll
        for (int c = 0; c < 2; ++c) { a3[c][0] = (floatx4)0.0f; a3[c][1] = (floatx4)0.0f; }
        gemmChunkH3(a3, wBuf[cur], bufA, ctb2, ptb, lane);
#pragma unroll
        for (int c = 0; c < 2; ++c) {
            const int ch0 = (ctb2 + c) * 16 + g * 4;
            const float4 bb = *reinterpret_cast<const float4*>(sBias + SB_HB3 + ch0);
#pragma unroll
            for (int pg = 0; pg < 2; ++pg) {
                const int pt2 = ptb + pg * 16 + m;
                floatx4 v = a3[c][pg];
                storeH4(bufB, pt2, ch0, fmaxf(v[0] + bb.x, 0.0f), fmaxf(v[1] + bb.y, 0.0f),
                        fmaxf(v[2] + bb.z, 0.0f), fmaxf(v[3] + bb.w, 0.0f));
            }
        }
    }
    __syncthreads();

    // ---- head4 (64->2) fp32 + flow combine + store (threads 0..127)
    if (t < 128) {
        const int pp = t >> 1, j = t & 1;
        float d = hb4[j];
#pragma unroll
        for (int i8 = 0; i8 < 8; ++i8) {
            const int c0 = i8 * 8;
            half8 hv = *reinterpret_cast<const half8*>(bufB + pp * 128 + (c0 ^ swz(pp)));
#pragma unroll
            for (int j2 = 0; j2 < 8; ++j2)
                d = fmaf((float)hv[j2], hw4[(c0 + j2) * 2 + j], d);
        }
        const int q = qbase + pp;
        const int rem = q - b * PTS_PER_IMG;
        const int gy = rem >> 9, gx = rem & 511;
        const float flow = sCps[j * 64 + pp] + d * (j == 0 ? 512.0f : 384.0f);
        out[(((size_t)b * 2 + j) * 384 + gy) * 512 + gx] = flow;
    }
#undef RESETQ
#undef STEP_END
#undef EPI_LOOP
}

extern "C" void kernel_launch(void* const* d_in, const int* in_sizes, int n_in,
                              void* d_out, int out_size, void* d_ws, size_t ws_size,
                              hipStream_t stream) {
    const float* feat_s8 = (const float*)d_in[1];
    const float* feat1_s8 = (const float*)d_in[2];
    const float* feat_s16 = (const float*)d_in[3];
    const float* ctx_s8 = (const float*)d_in[4];
    const float* coarse_flow = (const float*)d_in[5];
    const float* ctx_w = (const float*)d_in[6];
    const float* ctx_b = (const float*)d_in[7];
    const float* gate1 = (const float*)d_in[8];
    const float* ffn1_w1 = (const float*)d_in[9];
    const float* ffn1_b1 = (const float*)d_in[10];
    const float* ffn1_w2 = (const float*)d_in[11];
    const float* ffn1_b2 = (const float*)d_in[12];
    const float* s8_w = (const float*)d_in[13];
    const float* s8_b = (const float*)d_in[14];
    const float* gate2 = (const float*)d_in[15];
    const float* ffn2_w1 = (const float*)d_in[16];
    const float* ffn2_b1 = (const float*)d_in[17];
    const float* ffn2_w2 = (const float*)d_in[18];
    const float* ffn2_b2 = (const float*)d_in[19];
    const float* hw1 = (const float*)d_in[20];
    const float* hb1 = (const float*)d_in[21];
    const float* hw2 = (const float*)d_in[22];
    const float* hb2 = (const float*)d_in[23];
    const float* hw3 = (const float*)d_in[24];
    const float* hb3 = (const float*)d_in[25];
    const float* hw4 = (const float*)d_in[26];
    const float* hb4 = (const float*)d_in[27];
    float* out = (float*)d_out;
    _Float16* wsp = (_Float16*)d_ws;

    prepack_kernel<<<dim3(512), dim3(64), 0, stream>>>(
        ctx_w, ffn1_w1, ffn1_w2, s8_w, ffn2_w1, ffn2_w2, hw1, hw2, hw3, wsp);

    ifd_mfma<<<dim3(NBLOCKS), dim3(256), 0, stream>>>(
        feat_s8, feat1_s8, feat_s16, ctx_s8, coarse_flow,
        ctx_b, gate1, ffn1_b1, ffn1_b2, s8_b, gate2, ffn2_b1, ffn2_b2,
        hw1, hb1, hb2, hb3, hw4, hb4, wsp, out);
}

// Round 18
// 616.954 us; speedup vs baseline: 1.0490x; 1.0490x over previous
//
#include <hip/hip_runtime.h>
#include <math.h>

// ImplicitFlowDecoder FINAL (round 18) = r16 verbatim: the measured-best (643us),
// deterministic, proven-correct configuration.
// Architecture: f16 MFMA megakernel; prepacked weight fragments in d_ws; async
// double-buffered LDS weight staging (global_load_lds 16B); 64 pts/block,
// 4 waves in QUADRANT mapping (ct-half x pt-half: each weight ds_read feeds 2
// MFMAs); biases/gates in LDS; s_setprio(1) around MFMA clusters; 4 extra
// barriers guard the in-place-epilogue RAW/WAR hazards the quadrant mapping
// introduces. 2 blocks/CU co-residency hides stage/epilogue latency.
// r17's extra trims (scal rows in LDS, packed sIdx) measured neutral -> dropped.

typedef _Float16 half8 __attribute__((ext_vector_type(8)));
typedef _Float16 half4v __attribute__((ext_vector_type(4)));
typedef _Float16 half2v __attribute__((ext_vector_type(2)));
typedef float floatx4 __attribute__((ext_vector_type(4)));

#define NPOINTS_TOTAL (2 * 384 * 512)
#define PPB 64
#define NBLOCKS (NPOINTS_TOTAL / PPB)    // 6144
#define PTS_PER_IMG 196608
#define BLOCKS_PER_IMG 3072

#define WS_CTX   0
#define WS_F1W1  8192
#define WS_F1W2  40960
#define WS_S8    73728
#define WS_F2W1  90112
#define WS_F2W2  122880
#define WS_HW1   155648
#define WS_HW2   221184
#define WS_HW3   253952

// sBias layout (floats)
#define SB_CTXB  0
#define SB_GATE1 128
#define SB_F1B1  256
#define SB_F1B2  512
#define SB_S8B   640
#define SB_GATE2 768
#define SB_F2B1  896
#define SB_F2B2  1152
#define SB_HB1   1280
#define SB_HB2   1536
#define SB_HB3   1664
#define SB_TOT   1728

__device__ __forceinline__ float sigmoidf_(float x) { return 1.0f / (1.0f + expf(-x)); }
__device__ __forceinline__ float geluf_(float x) {
    const float ax = fabsf(x) * 0.70710678118654752f;
    const float t = 1.0f / fmaf(0.3275911f, ax, 1.0f);
    float poly = fmaf(t, 1.061405429f, -1.453152027f);
    poly = fmaf(t, poly, 1.421413741f);
    poly = fmaf(t, poly, -0.284496736f);
    poly = fmaf(t, poly, 0.254829592f);
    poly *= t;
    float er = 1.0f - poly * expf(-ax * ax);
    er = copysignf(er, x);
    return 0.5f * x * (1.0f + er);
}
__device__ __forceinline__ int swz(int pt) { return (pt & 15) << 3; }

// ---------------- prepack: W[K][N] fp32 -> f16 fragments -------------------
__global__ void prepack_kernel(const float* __restrict__ ctx_w, const float* __restrict__ f1w1,
                               const float* __restrict__ f1w2, const float* __restrict__ s8w,
                               const float* __restrict__ f2w1, const float* __restrict__ f2w2,
                               const float* __restrict__ hw1, const float* __restrict__ hw2,
                               const float* __restrict__ hw3, _Float16* __restrict__ ws) {
    const int bid = blockIdx.x;
    const int lane = threadIdx.x;
    const float* src; int N, CT, start; size_t ofsH;
    if (bid < 16)       { src = ctx_w; N = 128; CT = 8;  start = 0;   ofsH = WS_CTX; }
    else if (bid < 80)  { src = f1w1;  N = 256; CT = 16; start = 16;  ofsH = WS_F1W1; }
    else if (bid < 144) { src = f1w2;  N = 128; CT = 8;  start = 80;  ofsH = WS_F1W2; }
    else if (bid < 176) { src = s8w;   N = 128; CT = 8;  start = 144; ofsH = WS_S8; }
    else if (bid < 240) { src = f2w1;  N = 256; CT = 16; start = 176; ofsH = WS_F2W1; }
    else if (bid < 304) { src = f2w2;  N = 128; CT = 8;  start = 240; ofsH = WS_F2W2; }
    else if (bid < 432) { src = hw1;   N = 256; CT = 16; start = 304; ofsH = WS_HW1; }
    else if (bid < 496) { src = hw2;   N = 128; CT = 8;  start = 432; ofsH = WS_HW2; }
    else                { src = hw3;   N = 64;  CT = 4;  start = 496; ofsH = WS_HW3; }
    const int ti = bid - start;
    const int ks = ti / CT, ct = ti % CT;
    const int m = lane & 15, g = lane >> 4;
    const int kb = ks * 32 + g * 8;
    const int n = ct * 16 + m;
    half8 v;
#pragma unroll
    for (int j = 0; j < 8; ++j) v[j] = (_Float16)src[(size_t)(kb + j) * N + n];
    *reinterpret_cast<half8*>(ws + ofsH + (size_t)ti * 512 + lane * 8) = v;
}

// ---------------- async chunk staging ---------------------------------------
template <int NT, int CTc>
__device__ __forceinline__ void stageChunk(const _Float16* __restrict__ src, int cts,
                                           int ks0, int ct0, _Float16* wdst,
                                           int wid, int lane) {
#pragma unroll
    for (int jj = 0; jj < NT / 4; ++jj) {
        const int j = wid * (NT / 4) + jj;
        const int ks = j / CTc, ct = j - ks * CTc;
        const _Float16* s = src + (((size_t)(ks0 + ks) * cts + (ct0 + ct)) << 9) + lane * 8;
        _Float16* d = wdst + ((size_t)j << 9);
        __builtin_amdgcn_global_load_lds(
            (const __attribute__((address_space(1))) unsigned int*)s,
            (__attribute__((address_space(3))) unsigned int*)d, 16, 0, 0);
    }
}

// ---------------- GEMM chunk cores (quadrant: 4 ct tiles x 2 pt-groups) ----
template <int KSc>
__device__ __forceinline__ void gemmChunkQ(floatx4 (&acc)[4][2], const _Float16* wlds,
                                           const _Float16* sact, int kbase,
                                           int ctb, int ptb, int lane) {
    const int m = lane & 15, g = lane >> 4;
    const int pt0 = ptb + m, pt1 = pt0 + 16;
    const int s0 = swz(pt0), s1 = swz(pt1);
    const _Float16* wb = wlds + lane * 8;
    __builtin_amdgcn_s_setprio(1);
#pragma unroll
    for (int ks = 0; ks < KSc; ++ks) {
        const int k0 = (kbase + ks) * 32 + g * 8;
        half8 a0 = *reinterpret_cast<const half8*>(sact + pt0 * 128 + (k0 ^ s0));
        half8 a1 = *reinterpret_cast<const half8*>(sact + pt1 * 128 + (k0 ^ s1));
#pragma unroll
        for (int c = 0; c < 4; ++c) {
            half8 w = *reinterpret_cast<const half8*>(wb + ((size_t)(ks * 8 + ctb + c) << 9));
            acc[c][0] = __builtin_amdgcn_mfma_f32_16x16x32_f16(w, a0, acc[c][0], 0, 0, 0);
            acc[c][1] = __builtin_amdgcn_mfma_f32_16x16x32_f16(w, a1, acc[c][1], 0, 0, 0);
        }
    }
    __builtin_amdgcn_s_setprio(0);
}

template <int KSc>
__device__ __forceinline__ void gemmChunkRegBQ(floatx4 (&acc)[4][2], const _Float16* wlds,
                                               const half8 (&fr)[4][2], int frbase,
                                               int ctb, int lane) {
    const _Float16* wb = wlds + lane * 8;
    __builtin_amdgcn_s_setprio(1);
#pragma unroll
    for (int ks = 0; ks < KSc; ++ks) {
#pragma unroll
        for (int c = 0; c < 4; ++c) {
            half8 w = *reinterpret_cast<const half8*>(wb + ((size_t)(ks * 8 + ctb + c) << 9));
            acc[c][0] = __builtin_amdgcn_mfma_f32_16x16x32_f16(w, fr[frbase + ks][0], acc[c][0], 0, 0, 0);
            acc[c][1] = __builtin_amdgcn_mfma_f32_16x16x32_f16(w, fr[frbase + ks][1], acc[c][1], 0, 0, 0);
        }
    }
    __builtin_amdgcn_s_setprio(0);
}

// head3 (4 ct tiles total, CTc=4 layout): quadrant = 2 ct tiles x 2 pt-groups
__device__ __forceinline__ void gemmChunkH3(floatx4 (&acc)[2][2], const _Float16* wlds,
                                            const _Float16* sact, int ctb2, int ptb, int lane) {
    const int m = lane & 15, g = lane >> 4;
    const int pt0 = ptb + m, pt1 = pt0 + 16;
    const int s0 = swz(pt0), s1 = swz(pt1);
    const _Float16* wb = wlds + lane * 8;
    __builtin_amdgcn_s_setprio(1);
#pragma unroll
    for (int ks = 0; ks < 4; ++ks) {
        const int k0 = ks * 32 + g * 8;
        half8 a0 = *reinterpret_cast<const half8*>(sact + pt0 * 128 + (k0 ^ s0));
        half8 a1 = *reinterpret_cast<const half8*>(sact + pt1 * 128 + (k0 ^ s1));
#pragma unroll
        for (int c = 0; c < 2; ++c) {
            half8 w = *reinterpret_cast<const half8*>(wb + ((size_t)(ks * 4 + ctb2 + c) << 9));
            acc[c][0] = __builtin_amdgcn_mfma_f32_16x16x32_f16(w, a0, acc[c][0], 0, 0, 0);
            acc[c][1] = __builtin_amdgcn_mfma_f32_16x16x32_f16(w, a1, acc[c][1], 0, 0, 0);
        }
    }
    __builtin_amdgcn_s_setprio(0);
}

__device__ __forceinline__ void loadFragsQ(half8 (&fr)[4][2], const _Float16* sact,
                                           int ptb, int lane) {
    const int m = lane & 15, g = lane >> 4;
    const int pt0 = ptb + m, pt1 = pt0 + 16;
    const int s0 = swz(pt0), s1 = swz(pt1);
#pragma unroll
    for (int ks = 0; ks < 4; ++ks) {
        const int k0 = ks * 32 + g * 8;
        fr[ks][0] = *reinterpret_cast<const half8*>(sact + pt0 * 128 + (k0 ^ s0));
        fr[ks][1] = *reinterpret_cast<const half8*>(sact + pt1 * 128 + (k0 ^ s1));
    }
}

__device__ __forceinline__ void storeH4(_Float16* dst, int pt, int ch0,
                                        float o0, float o1, float o2, float o3) {
    half4v hv;
    hv[0] = (_Float16)o0; hv[1] = (_Float16)o1; hv[2] = (_Float16)o2; hv[3] = (_Float16)o3;
    *reinterpret_cast<half4v*>(dst + pt * 128 + (ch0 ^ swz(pt))) = hv;
}
__device__ __forceinline__ half4v loadH4(const _Float16* src, int pt, int ch0) {
    return *reinterpret_cast<const half4v*>(src + pt * 128 + (ch0 ^ swz(pt)));
}

// ---------------- main kernel ----------------------------------------------
__global__ void __launch_bounds__(256, 2)
ifd_mfma(const float* __restrict__ feat_s8, const float* __restrict__ feat1_s8,
         const float* __restrict__ feat_s16, const float* __restrict__ ctx_s8,
         const float* __restrict__ coarse_flow,
         const float* __restrict__ ctx_b, const float* __restrict__ gate1,
         const float* __restrict__ ffn1_b1, const float* __restrict__ ffn1_b2,
         const float* __restrict__ s8_b, const float* __restrict__ gate2,
         const float* __restrict__ ffn2_b1, const float* __restrict__ ffn2_b2,
         const float* __restrict__ hw1, const float* __restrict__ hb1,
         const float* __restrict__ hb2, const float* __restrict__ hb3,
         const float* __restrict__ hw4, const float* __restrict__ hb4,
         const _Float16* __restrict__ wsp, float* __restrict__ out) {
    __shared__ __align__(16) _Float16 bufA[64 * 128];      // 16KB
    __shared__ __align__(16) _Float16 bufB[64 * 128];      // 16KB
    __shared__ __align__(16) _Float16 wBuf[2][8192];       // 2x16KB weight chunks
    __shared__ __align__(16) float sBias[SB_TOT];          // 6.9KB
    __shared__ float sScal[4 * 64];
    __shared__ float sCps[2 * 64];
    __shared__ int   sIdx[3 * 4 * 64];
    __shared__ float sWgt[3 * 2 * 64];

    const int t = threadIdx.x;
    const int lane = t & 63, wid = t >> 6;           // 4 waves
    const int m = lane & 15, g = lane >> 4;
    const int ctb = (wid & 1) * 4;                    // ct-tile quadrant base (0 or 4)
    const int ptb = (wid >> 1) * 32;                  // point quadrant base (0 or 32)
    const int b = blockIdx.x / BLOCKS_PER_IMG;
    const int qbase = blockIdx.x * PPB;
    const float CHI = 1.0f - 1e-6f;

    // ---------- biases/gates -> LDS
    if (t < 128) {
        sBias[SB_CTXB + t] = ctx_b[t];
        sBias[SB_GATE1 + t] = gate1[t];
        sBias[SB_F1B2 + t] = ffn1_b2[t];
        sBias[SB_S8B + t] = s8_b[t];
        sBias[SB_GATE2 + t] = gate2[t];
        sBias[SB_F2B2 + t] = ffn2_b2[t];
        sBias[SB_HB2 + t] = hb2[t];
    }
    sBias[SB_F1B1 + t] = ffn1_b1[t];
    sBias[SB_F2B1 + t] = ffn2_b1[t];
    sBias[SB_HB1 + t] = hb1[t];
    if (t < 64) sBias[SB_HB3 + t] = hb3[t];

    // ---------- coords + coarse flow + warp (threads 0..63, 1 pt each)
    if (t < 64) {
        const int p = t;
        const int rem = qbase + p - b * PTS_PER_IMG;
        const int gy = rem >> 9, gx = rem & 511;
        float cnx = fminf(fmaxf(2.0f * ((float)gx + 0.5f) / 512.0f - 1.0f, -CHI), CHI);
        float cny = fminf(fmaxf(2.0f * ((float)gy + 0.5f) / 384.0f - 1.0f, -CHI), CHI);

        auto mkc = [](float cn, float Sf, int Smax, int& i0, int& i1, float& w) {
            float x = fminf(fmaxf(((cn + 1.0f) * Sf - 1.0f) * 0.5f, 0.0f), Sf - 1.0f);
            float xf = floorf(x);
            w = x - xf;
            i0 = (int)xf;
            i1 = (i0 + 1 > Smax) ? Smax : i0 + 1;
        };
        auto storeSet = [&](int s, int x0, int x1, int y0, int y1, float wx, float wy) {
            sIdx[s * 256 + 0 * 64 + p] = x0; sIdx[s * 256 + 1 * 64 + p] = x1;
            sIdx[s * 256 + 2 * 64 + p] = y0; sIdx[s * 256 + 3 * 64 + p] = y1;
            sWgt[s * 128 + p] = wx; sWgt[s * 128 + 64 + p] = wy;
        };

        int x0, x1, y0, y1; float wx, wy;
        mkc(cnx, 64.0f, 63, x0, x1, wx);
        mkc(cny, 48.0f, 47, y0, y1, wy);
        storeSet(0, x0, x1, y0, y1, wx, wy);

        int X0, X1, Y0, Y1; float WX, WY;
        mkc(cnx, 32.0f, 31, X0, X1, WX);
        mkc(cny, 24.0f, 23, Y0, Y1, WY);
        storeSet(1, X0, X1, Y0, Y1, WX, WY);

        const float w00 = (1.0f - wx) * (1.0f - wy), w01 = wx * (1.0f - wy);
        const float w10 = (1.0f - wx) * wy, w11 = wx * wy;
        const int i00 = y0 * 64 + x0, i01 = y0 * 64 + x1, i10 = y1 * 64 + x0, i11 = y1 * 64 + x1;
        const float* cf = coarse_flow + (size_t)b * 6144;
        float c0 = (cf[i00] * w00 + cf[i01] * w01 + cf[i10] * w10 + cf[i11] * w11) * 8.0f;
        const float* cf1 = cf + 3072;
        float c1 = (cf1[i00] * w00 + cf1[i01] * w01 + cf1[i10] * w10 + cf1[i11] * w11) * 8.0f;
        sCps[p] = c0; sCps[64 + p] = c1;
        sScal[p] = cnx; sScal[64 + p] = cny;
        sScal[128 + p] = c0 / 512.0f; sScal[192 + p] = c1 / 384.0f;

        float wxn = fminf(fmaxf(cnx + 2.0f * c0 / 512.0f, -CHI), CHI);
        float wyn = fminf(fmaxf(cny + 2.0f * c1 / 384.0f, -CHI), CHI);
        int u0, u1, v0, v1; float uw, vw;
        mkc(wxn, 64.0f, 63, u0, u1, uw);
        mkc(wyn, 48.0f, 47, v0, v1, vw);
        storeSet(2, u0, u1, v0, v1, uw, vw);
    }

    // prologue: issue first chunk stage into wBuf[0]
    stageChunk<16, 8>(wsp + WS_CTX, 8, 0, 0, wBuf[0], wid, lane);
    __syncthreads();

    // thread t samples point (t&63), channel-quarter (t>>6)
    auto sampleMap = [&](const float* __restrict__ mapB, int C, int HW, int Wd, int set,
                         _Float16* dst) {
        const int pt = t & 63, hs = t >> 6;
        const int x0 = sIdx[set * 256 + pt], x1 = sIdx[set * 256 + 64 + pt];
        const int y0 = sIdx[set * 256 + 128 + pt], y1 = sIdx[set * 256 + 192 + pt];
        const float wx = sWgt[set * 128 + pt], wy = sWgt[set * 128 + 64 + pt];
        const float w00 = (1.0f - wx) * (1.0f - wy), w01 = wx * (1.0f - wy);
        const float w10 = (1.0f - wx) * wy, w11 = wx * wy;
        const int i00 = y0 * Wd + x0, i01 = y0 * Wd + x1, i10 = y1 * Wd + x0, i11 = y1 * Wd + x1;
        const int np = C >> 3;
#pragma unroll 4
        for (int i = 0; i < np; ++i) {
            const int c0 = hs * (C >> 2) + 2 * i;
            const float* p0 = mapB + (size_t)c0 * HW;
            const float* p1 = p0 + HW;
            float v0 = p0[i00] * w00 + p0[i01] * w01 + p0[i10] * w10 + p0[i11] * w11;
            float v1 = p1[i00] * w00 + p1[i01] * w01 + p1[i10] * w10 + p1[i11] * w11;
            half2v hv; hv[0] = (_Float16)v0; hv[1] = (_Float16)v1;
            *reinterpret_cast<half2v*>(dst + pt * 128 + (c0 ^ swz(pt))) = hv;
        }
    };

    // ---------- sample f8 -> bufA, fctx -> bufB[:,0:64]
    sampleMap(feat_s8 + (size_t)b * 128 * 3072, 128, 3072, 64, 0, bufA);
    sampleMap(ctx_s8 + (size_t)b * 64 * 3072, 64, 3072, 64, 0, bufB);
    __syncthreads();

    int cur = 0;
    floatx4 acc[4][2];

#define RESETQ() do { _Pragma("unroll") for (int _c = 0; _c < 4; ++_c) \
    { acc[_c][0] = (floatx4)0.0f; acc[_c][1] = (floatx4)0.0f; } } while (0)
#define STEP_END() do { __syncthreads(); cur ^= 1; } while (0)

#define EPI_LOOP(BODY) do { \
    _Pragma("unroll") for (int c = 0; c < 4; ++c) { \
        const int ch0 = (ctb + c) * 16 + g * 4; \
        _Pragma("unroll") for (int pg = 0; pg < 2; ++pg) { \
            const int pt2 = ptb + pg * 16 + m; \
            floatx4 v = acc[c][pg]; \
            BODY \
        } } } while (0)

    // ---- ctx: C0 (2ks, bufB) + epi gate1 -> bufA (residual own quadrant, safe)
    stageChunk<16, 8>(wsp + WS_F1W1, 16, 0, 0, wBuf[cur ^ 1], wid, lane);    // C1
    RESETQ();
    gemmChunkQ<2>(acc, wBuf[cur], bufB, 0, ctb, ptb, lane);
    EPI_LOOP({
        const float4 bb = *reinterpret_cast<const float4*>(sBias + SB_CTXB + ch0);
        const float4 gg = *reinterpret_cast<const float4*>(sBias + SB_GATE1 + ch0);
        half4v rv = loadH4(bufA, pt2, ch0);
        storeH4(bufA, pt2, ch0,
                (float)rv[0] + sigmoidf_(gg.x) * (v[0] + bb.x),
                (float)rv[1] + sigmoidf_(gg.y) * (v[1] + bb.y),
                (float)rv[2] + sigmoidf_(gg.z) * (v[2] + bb.z),
                (float)rv[3] + sigmoidf_(gg.w) * (v[3] + bb.w));
    });
    STEP_END();

    // ---- ffn1_w1 half0: C1 + C2, epi gelu -> bufB (bufB dead, safe)
    stageChunk<16, 8>(wsp + WS_F1W1, 16, 2, 0, wBuf[cur ^ 1], wid, lane);    // C2
    RESETQ();
    gemmChunkQ<2>(acc, wBuf[cur], bufA, 0, ctb, ptb, lane);
    STEP_END();
    stageChunk<16, 8>(wsp + WS_F1W1, 16, 0, 8, wBuf[cur ^ 1], wid, lane);    // C3
    gemmChunkQ<2>(acc, wBuf[cur], bufA, 2, ctb, ptb, lane);
    EPI_LOOP({
        const float4 bb = *reinterpret_cast<const float4*>(sBias + SB_F1B1 + ch0);
        storeH4(bufB, pt2, ch0, geluf_(v[0] + bb.x), geluf_(v[1] + bb.y),
                geluf_(v[2] + bb.z), geluf_(v[3] + bb.w));
    });
    STEP_END();

    // ---- ffn1_w1 half1: C3 + C4, epi gelu -> bufA IN-PLACE (barrier before write)
    stageChunk<16, 8>(wsp + WS_F1W1, 16, 2, 8, wBuf[cur ^ 1], wid, lane);    // C4
    RESETQ();
    gemmChunkQ<2>(acc, wBuf[cur], bufA, 0, ctb, ptb, lane);
    STEP_END();
    stageChunk<16, 8>(wsp + WS_F1W2, 8, 0, 0, wBuf[cur ^ 1], wid, lane);     // C5
    gemmChunkQ<2>(acc, wBuf[cur], bufA, 2, ctb, ptb, lane);
    __syncthreads();   // RACE FIX: partner still reading bufA ch64-127
    EPI_LOOP({
        const float4 bb = *reinterpret_cast<const float4*>(sBias + SB_F1B1 + 128 + ch0);
        storeH4(bufA, pt2, ch0, geluf_(v[0] + bb.x), geluf_(v[1] + bb.y),
                geluf_(v[2] + bb.z), geluf_(v[3] + bb.w));
    });
    STEP_END();

    // ---- ffn1_w2: C5-C8 (bufB k0-3, bufA k0-3), epi -> bufA IN-PLACE
    stageChunk<16, 8>(wsp + WS_F1W2, 8, 2, 0, wBuf[cur ^ 1], wid, lane);     // C6
    RESETQ();
    gemmChunkQ<2>(acc, wBuf[cur], bufB, 0, ctb, ptb, lane);
    STEP_END();
    stageChunk<16, 8>(wsp + WS_F1W2, 8, 4, 0, wBuf[cur ^ 1], wid, lane);     // C7
    gemmChunkQ<2>(acc, wBuf[cur], bufB, 2, ctb, ptb, lane);
    STEP_END();
    stageChunk<16, 8>(wsp + WS_F1W2, 8, 6, 0, wBuf[cur ^ 1], wid, lane);     // C8
    gemmChunkQ<2>(acc, wBuf[cur], bufA, 0, ctb, ptb, lane);
    STEP_END();
    stageChunk<16, 8>(wsp + WS_S8, 8, 0, 0, wBuf[cur ^ 1], wid, lane);       // C9
    gemmChunkQ<2>(acc, wBuf[cur], bufA, 2, ctb, ptb, lane);
    __syncthreads();   // RACE FIX
    EPI_LOOP({
        const float4 bb = *reinterpret_cast<const float4*>(sBias + SB_F1B2 + ch0);
        storeH4(bufA, pt2, ch0, v[0] + bb.x, v[1] + bb.y, v[2] + bb.z, v[3] + bb.w);
    });
    STEP_END();

    // ---- sample f16 -> bufB
    sampleMap(feat_s16 + (size_t)b * 128 * 768, 128, 768, 32, 1, bufB);
    __syncthreads();

    // ---- s8: C9 + C10 (bufA), epi gate2 + f16 -> bufB (residual own quadrant, safe)
    stageChunk<16, 8>(wsp + WS_S8, 8, 2, 0, wBuf[cur ^ 1], wid, lane);       // C10
    RESETQ();
    gemmChunkQ<2>(acc, wBuf[cur], bufA, 0, ctb, ptb, lane);
    STEP_END();
    stageChunk<16, 8>(wsp + WS_F2W1, 16, 0, 0, wBuf[cur ^ 1], wid, lane);    // C11
    gemmChunkQ<2>(acc, wBuf[cur], bufA, 2, ctb, ptb, lane);
    EPI_LOOP({
        const float4 bb = *reinterpret_cast<const float4*>(sBias + SB_S8B + ch0);
        const float4 gg = *reinterpret_cast<const float4*>(sBias + SB_GATE2 + ch0);
        half4v rv = loadH4(bufB, pt2, ch0);
        storeH4(bufB, pt2, ch0,
                (float)rv[0] + sigmoidf_(gg.x) * (v[0] + bb.x),
                (float)rv[1] + sigmoidf_(gg.y) * (v[1] + bb.y),
                (float)rv[2] + sigmoidf_(gg.z) * (v[2] + bb.z),
                (float)rv[3] + sigmoidf_(gg.w) * (v[3] + bb.w));
    });
    STEP_END();

    // ---- ffn2_w1 half0: C11 + C12 (bufB), epi gelu -> bufA (bufA dead, safe)
    stageChunk<16, 8>(wsp + WS_F2W1, 16, 2, 0, wBuf[cur ^ 1], wid, lane);    // C12
    RESETQ();
    gemmChunkQ<2>(acc, wBuf[cur], bufB, 0, ctb, ptb, lane);
    STEP_END();
    stageChunk<16, 8>(wsp + WS_F2W1, 16, 0, 8, wBuf[cur ^ 1], wid, lane);    // C13
    gemmChunkQ<2>(acc, wBuf[cur], bufB, 2, ctb, ptb, lane);
    EPI_LOOP({
        const float4 bb = *reinterpret_cast<const float4*>(sBias + SB_F2B1 + ch0);
        storeH4(bufA, pt2, ch0, geluf_(v[0] + bb.x), geluf_(v[1] + bb.y),
                geluf_(v[2] + bb.z), geluf_(v[3] + bb.w));
    });
    STEP_END();

    // ---- ffn2_w1 half1: C13 + C14 (bufB), epi gelu -> bufB IN-PLACE
    stageChunk<16, 8>(wsp + WS_F2W1, 16, 2, 8, wBuf[cur ^ 1], wid, lane);    // C14
    RESETQ();
    gemmChunkQ<2>(acc, wBuf[cur], bufB, 0, ctb, ptb, lane);
    STEP_END();
    stageChunk<16, 8>(wsp + WS_F2W2, 8, 0, 0, wBuf[cur ^ 1], wid, lane);     // C15
    gemmChunkQ<2>(acc, wBuf[cur], bufB, 2, ctb, ptb, lane);
    __syncthreads();   // RACE FIX
    EPI_LOOP({
        const float4 bb = *reinterpret_cast<const float4*>(sBias + SB_F2B1 + 128 + ch0);
        storeH4(bufB, pt2, ch0, geluf_(v[0] + bb.x), geluf_(v[1] + bb.y),
                geluf_(v[2] + bb.z), geluf_(v[3] + bb.w));
    });
    STEP_END();

    // ---- ffn2_w2: C15-C18 (bufA k0-3, bufB k0-3), epi fused -> bufB IN-PLACE
    stageChunk<16, 8>(wsp + WS_F2W2, 8, 2, 0, wBuf[cur ^ 1], wid, lane);     // C16
    RESETQ();
    gemmChunkQ<2>(acc, wBuf[cur], bufA, 0, ctb, ptb, lane);
    STEP_END();
    stageChunk<16, 8>(wsp + WS_F2W2, 8, 4, 0, wBuf[cur ^ 1], wid, lane);     // C17
    gemmChunkQ<2>(acc, wBuf[cur], bufA, 2, ctb, ptb, lane);
    STEP_END();
    stageChunk<16, 8>(wsp + WS_F2W2, 8, 6, 0, wBuf[cur ^ 1], wid, lane);     // C18
    gemmChunkQ<2>(acc, wBuf[cur], bufB, 0, ctb, ptb, lane);
    STEP_END();
    stageChunk<16, 8>(wsp + WS_HW1, 16, 0, 0, wBuf[cur ^ 1], wid, lane);     // C19
    gemmChunkQ<2>(acc, wBuf[cur], bufB, 2, ctb, ptb, lane);
    __syncthreads();   // RACE FIX
    EPI_LOOP({
        const float4 bb = *reinterpret_cast<const float4*>(sBias + SB_F2B2 + ch0);
        storeH4(bufB, pt2, ch0, v[0] + bb.x, v[1] + bb.y, v[2] + bb.z, v[3] + bb.w);
    });
    STEP_END();

    // ---- sample f1w -> bufA
    sampleMap(feat1_s8 + (size_t)b * 128 * 3072, 128, 3072, 64, 2, bufA);
    __syncthreads();

    // ---- head1 hf0: C19,C20 (bufB) + C21,C22 (f1w regs), epi scal+relu -> bufA
    half8 fr[4][2];
    loadFragsQ(fr, bufA, ptb, lane);   // all waves load before any barrier-crossing write
    stageChunk<16, 8>(wsp + WS_HW1, 16, 2, 0, wBuf[cur ^ 1], wid, lane);     // C20
    RESETQ();
    gemmChunkQ<2>(acc, wBuf[cur], bufB, 0, ctb, ptb, lane);
    STEP_END();
    stageChunk<16, 8>(wsp + WS_HW1, 16, 4, 0, wBuf[cur ^ 1], wid, lane);     // C21
    gemmChunkQ<2>(acc, wBuf[cur], bufB, 2, ctb, ptb, lane);
    STEP_END();
    stageChunk<16, 8>(wsp + WS_HW1, 16, 6, 0, wBuf[cur ^ 1], wid, lane);     // C22
    gemmChunkRegBQ<2>(acc, wBuf[cur], fr, 0, ctb, lane);
    STEP_END();
    stageChunk<16, 8>(wsp + WS_HW1, 16, 0, 8, wBuf[cur ^ 1], wid, lane);     // C23
    gemmChunkRegBQ<2>(acc, wBuf[cur], fr, 2, ctb, lane);
#pragma unroll
    for (int c = 0; c < 4; ++c) {
        const int ch0 = (ctb + c) * 16 + g * 4;
#pragma unroll
        for (int jj = 0; jj < 4; ++jj) {
            const float4 wj = *reinterpret_cast<const float4*>(hw1 + (size_t)(256 + jj) * 256 + ch0);
#pragma unroll
            for (int pg = 0; pg < 2; ++pg) {
                const float s = sScal[jj * 64 + ptb + pg * 16 + m];
                floatx4 v = acc[c][pg];
                v[0] = fmaf(wj.x, s, v[0]); v[1] = fmaf(wj.y, s, v[1]);
                v[2] = fmaf(wj.z, s, v[2]); v[3] = fmaf(wj.w, s, v[3]);
                acc[c][pg] = v;
            }
        }
    }
    EPI_LOOP({
        const float4 bb = *reinterpret_cast<const float4*>(sBias + SB_HB1 + ch0);
        storeH4(bufA, pt2, ch0, fmaxf(v[0] + bb.x, 0.0f), fmaxf(v[1] + bb.y, 0.0f),
                fmaxf(v[2] + bb.z, 0.0f), fmaxf(v[3] + bb.w, 0.0f));
    });
    STEP_END();

    // ---- head1 hf1: C23,C24 (bufB) + C25,C26 (f1w regs), epi scal+relu -> bufB
    stageChunk<16, 8>(wsp + WS_HW1, 16, 2, 8, wBuf[cur ^ 1], wid, lane);     // C24
    RESETQ();
    gemmChunkQ<2>(acc, wBuf[cur], bufB, 0, ctb, ptb, lane);
    STEP_END();
    stageChunk<16, 8>(wsp + WS_HW1, 16, 4, 8, wBuf[cur ^ 1], wid, lane);     // C25
    gemmChunkQ<2>(acc, wBuf[cur], bufB, 2, ctb, ptb, lane);
    STEP_END();
    stageChunk<16, 8>(wsp + WS_HW1, 16, 6, 8, wBuf[cur ^ 1], wid, lane);     // C26
    gemmChunkRegBQ<2>(acc, wBuf[cur], fr, 0, ctb, lane);
    STEP_END();
    stageChunk<16, 8>(wsp + WS_HW2, 8, 0, 0, wBuf[cur ^ 1], wid, lane);      // C27
    gemmChunkRegBQ<2>(acc, wBuf[cur], fr, 2, ctb, lane);
#pragma unroll
    for (int c = 0; c < 4; ++c) {
        const int ch0 = (ctb + c) * 16 + g * 4;
#pragma unroll
        for (int jj = 0; jj < 4; ++jj) {
            const float4 wj = *reinterpret_cast<const float4*>(hw1 + (size_t)(256 + jj) * 256 + 128 + ch0);
#pragma unroll
            for (int pg = 0; pg < 2; ++pg) {
                const float s = sScal[jj * 64 + ptb + pg * 16 + m];
                floatx4 v = acc[c][pg];
                v[0] = fmaf(wj.x, s, v[0]); v[1] = fmaf(wj.y, s, v[1]);
                v[2] = fmaf(wj.z, s, v[2]); v[3] = fmaf(wj.w, s, v[3]);
                acc[c][pg] = v;
            }
        }
    }
    EPI_LOOP({
        const float4 bb = *reinterpret_cast<const float4*>(sBias + SB_HB1 + 128 + ch0);
        storeH4(bufB, pt2, ch0, fmaxf(v[0] + bb.x, 0.0f), fmaxf(v[1] + bb.y, 0.0f),
                fmaxf(v[2] + bb.z, 0.0f), fmaxf(v[3] + bb.w, 0.0f));
    });
    STEP_END();

    // ---- head2: C27-C30 (bufA k0-3, bufB k0-3), epi relu -> bufA
    stageChunk<16, 8>(wsp + WS_HW2, 8, 2, 0, wBuf[cur ^ 1], wid, lane);      // C28
    RESETQ();
    gemmChunkQ<2>(acc, wBuf[cur], bufA, 0, ctb, ptb, lane);
    STEP_END();
    stageChunk<16, 8>(wsp + WS_HW2, 8, 4, 0, wBuf[cur ^ 1], wid, lane);      // C29
    gemmChunkQ<2>(acc, wBuf[cur], bufA, 2, ctb, ptb, lane);
    STEP_END();
    stageChunk<16, 8>(wsp + WS_HW2, 8, 6, 0, wBuf[cur ^ 1], wid, lane);      // C30
    gemmChunkQ<2>(acc, wBuf[cur], bufB, 0, ctb, ptb, lane);
    STEP_END();
    stageChunk<16, 4>(wsp + WS_HW3, 4, 0, 0, wBuf[cur ^ 1], wid, lane);      // C31 (all 16 tiles)
    gemmChunkQ<2>(acc, wBuf[cur], bufB, 2, ctb, ptb, lane);
    EPI_LOOP({
        const float4 bb = *reinterpret_cast<const float4*>(sBias + SB_HB2 + ch0);
        storeH4(bufA, pt2, ch0, fmaxf(v[0] + bb.x, 0.0f), fmaxf(v[1] + bb.y, 0.0f),
                fmaxf(v[2] + bb.z, 0.0f), fmaxf(v[3] + bb.w, 0.0f));
    });
    STEP_END();

    // ---- head3: C31 (4ks x 4ct layout, bufA), quadrant 2ct x 2pg -> bufB[:,0:64]
    {
        const int ctb2 = (wid & 1) * 2;
        floatx4 a3[2][2];
#pragma unroll
        for (int c = 0; c < 2; ++c) { a3[c][0] = (floatx4)0.0f; a3[c][1] = (floatx4)0.0f; }
        gemmChunkH3(a3, wBuf[cur], bufA, ctb2, ptb, lane);
#pragma unroll
        for (int c = 0; c < 2; ++c) {
            const int ch0 = (ctb2 + c) * 16 + g * 4;
            const float4 bb = *reinterpret_cast<const float4*>(sBias + SB_HB3 + ch0);
#pragma unroll
            for (int pg = 0; pg < 2; ++pg) {
                const int pt2 = ptb + pg * 16 + m;
                floatx4 v = a3[c][pg];
                storeH4(bufB, pt2, ch0, fmaxf(v[0] + bb.x, 0.0f), fmaxf(v[1] + bb.y, 0.0f),
                        fmaxf(v[2] + bb.z, 0.0f), fmaxf(v[3] + bb.w, 0.0f));
            }
        }
    }
    __syncthreads();

    // ---- head4 (64->2) fp32 + flow combine + store (threads 0..127)
    if (t < 128) {
        const int pp = t >> 1, j = t & 1;
        float d = hb4[j];
#pragma unroll
        for (int i8 = 0; i8 < 8; ++i8) {
            const int c0 = i8 * 8;
            half8 hv = *reinterpret_cast<const half8*>(bufB + pp * 128 + (c0 ^ swz(pp)));
#pragma unroll
            for (int j2 = 0; j2 < 8; ++j2)
                d = fmaf((float)hv[j2], hw4[(c0 + j2) * 2 + j], d);
        }
        const int q = qbase + pp;
        const int rem = q - b * PTS_PER_IMG;
        const int gy = rem >> 9, gx = rem & 511;
        const float flow = sCps[j * 64 + pp] + d * (j == 0 ? 512.0f : 384.0f);
        out[(((size_t)b * 2 + j) * 384 + gy) * 512 + gx] = flow;
    }
#undef RESETQ
#undef STEP_END
#undef EPI_LOOP
}

extern "C" void kernel_launch(void* const* d_in, const int* in_sizes, int n_in,
                              void* d_out, int out_size, void* d_ws, size_t ws_size,
                              hipStream_t stream) {
    const float* feat_s8 = (const float*)d_in[1];
    const float* feat1_s8 = (const float*)d_in[2];
    const float* feat_s16 = (const float*)d_in[3];
    const float* ctx_s8 = (const float*)d_in[4];
    const float* coarse_flow = (const float*)d_in[5];
    const float* ctx_w = (const float*)d_in[6];
    const float* ctx_b = (const float*)d_in[7];
    const float* gate1 = (const float*)d_in[8];
    const float* ffn1_w1 = (const float*)d_in[9];
    const float* ffn1_b1 = (const float*)d_in[10];
    const float* ffn1_w2 = (const float*)d_in[11];
    const float* ffn1_b2 = (const float*)d_in[12];
    const float* s8_w = (const float*)d_in[13];
    const float* s8_b = (const float*)d_in[14];
    const float* gate2 = (const float*)d_in[15];
    const float* ffn2_w1 = (const float*)d_in[16];
    const float* ffn2_b1 = (const float*)d_in[17];
    const float* ffn2_w2 = (const float*)d_in[18];
    const float* ffn2_b2 = (const float*)d_in[19];
    const float* hw1 = (const float*)d_in[20];
    const float* hb1 = (const float*)d_in[21];
    const float* hw2 = (const float*)d_in[22];
    const float* hb2 = (const float*)d_in[23];
    const float* hw3 = (const float*)d_in[24];
    const float* hb3 = (const float*)d_in[25];
    const float* hw4 = (const float*)d_in[26];
    const float* hb4 = (const float*)d_in[27];
    float* out = (float*)d_out;
    _Float16* wsp = (_Float16*)d_ws;

    prepack_kernel<<<dim3(512), dim3(64), 0, stream>>>(
        ctx_w, ffn1_w1, ffn1_w2, s8_w, ffn2_w1, ffn2_w2, hw1, hw2, hw3, wsp);

    ifd_mfma<<<dim3(NBLOCKS), dim3(256), 0, stream>>>(
        feat_s8, feat1_s8, feat_s16, ctx_s8, coarse_flow,
        ctx_b, gate1, ffn1_b1, ffn1_b2, s8_b, gate2, ffn2_b1, ffn2_b2,
        hw1, hb1, hb2, hb3, hw4, hb4, wsp, out);
}